// Round 14
// baseline (1573.082 us; speedup 1.0000x reference)
//
#include <hip/hip_runtime.h>

#define TT 2048
#define BB 256
#define FF 64
#define HH 128
#define NT 256            // 4 waves; wave w owns units [32w, 32w+32)
#define MROWS 16          // batch rows per block -> M dim of MFMA
#define NBLK (BB / MROWS) // 16 blocks
#define RS (BB * FF / 4)  // x row stride in float4

typedef _Float16 half8 __attribute__((ext_vector_type(8)));
typedef _Float16 half4 __attribute__((ext_vector_type(4)));
typedef _Float16 h2v   __attribute__((ext_vector_type(2)));
typedef float    f32x4 __attribute__((ext_vector_type(4)));

#if __has_builtin(__builtin_amdgcn_rcpf)
#define FRCP(v) __builtin_amdgcn_rcpf(v)
#else
#define FRCP(v) (1.0f / (v))
#endif

// D = A(16x32 f16) * B(32x16 f16) + C(f32). A/B k-packing is consistent
// between operands, so the internal k order cancels; C/D layout is the
// verified col=lane&15, row=(lane>>4)*4+reg.
__device__ __forceinline__ f32x4 mf(f32x4 a, f32x4 b, f32x4 c) {
  return __builtin_amdgcn_mfma_f32_16x16x32_f16(
      __builtin_bit_cast(half8, a), __builtin_bit_cast(half8, b), c, 0, 0, 0);
}

// Hot-loop barrier without the vmcnt(0) drain (r9: proven equivalent).
__device__ __forceinline__ void step_barrier() {
  asm volatile("s_waitcnt lgkmcnt(0)" ::: "memory");
  __builtin_amdgcn_s_barrier();
  __builtin_amdgcn_sched_barrier(0);
}

// In-loop pins (r7-proven): B-fragments stay loop-carried in VGPRs.
#define PINS()                                                              \
  do {                                                                      \
    _Pragma("unroll") for (int _t = 0; _t < 2; ++_t) {                      \
      _Pragma("unroll") for (int _k = 0; _k < 4; ++_k) {                    \
        asm volatile("" : "+v"(Bhr[_t][_k]), "+v"(Bhz[_t][_k]),             \
                          "+v"(Bhn[_t][_k]));                               \
      }                                                                     \
      _Pragma("unroll") for (int _k = 0; _k < 2; ++_k) {                    \
        asm volatile("" : "+v"(Bxr[_t][_k]), "+v"(Bxz[_t][_k]),             \
                          "+v"(Bxn[_t][_k]));                               \
      }                                                                     \
    }                                                                       \
  } while (0)

__global__ void __launch_bounds__(NT)
__attribute__((amdgpu_waves_per_eu(1, 1)))
gru_scan_kernel(const float* __restrict__ x,     // [T,B,F]
                const float* __restrict__ Wi,    // [F,3H] r|z|n
                const float* __restrict__ bi,    // [3H]
                const float* __restrict__ Whrz,  // [H,2H] r|z
                const float* __restrict__ Whn,   // [H,H]
                const float* __restrict__ bn,    // [H]
                float* __restrict__ out)         // [T,B,H]
{
  const int tid   = threadIdx.x;
  const int w     = tid >> 6;     // wave 0..3
  const int l     = tid & 63;
  const int n16   = l & 15;       // n-index within tile / A-row m
  const int q     = l >> 4;       // k-chunk group
  const int brow0 = blockIdx.x * MROWS;

  // A-operand staging (f16). Rows XOR-swizzled: byte ^= ((row&7)<<4).
  __shared__ __align__(16) _Float16 h_lds[2][MROWS * HH];  // 8 KB
  __shared__ __align__(16) _Float16 x_lds[4][MROWS * FF];  // 8 KB

  // ---- B-fragments in registers: wave w, tile tu covers units
  // g = 32w+16tu+n16. h k-space permuted: phys p holds unit
  // pi(p) = 32*(p>>5) + 16*(p&1) + ((p&31)>>1)  (so units g,g+16 pack
  // adjacently for the h'-write). x k-space natural. ----
  f32x4 Bhr[2][4], Bhz[2][4], Bhn[2][4];
  f32x4 Bxr[2][2], Bxz[2][2], Bxn[2][2];
  f32x4 biasR[2], biasZ[2], biasHN[2], biasXN[2];
  #pragma unroll
  for (int tu = 0; tu < 2; ++tu) {
    const int g = 32 * w + 16 * tu + n16;
    #pragma unroll
    for (int kt = 0; kt < 4; ++kt) {
      half8 fr, fz, fn;
      #pragma unroll
      for (int j = 0; j < 8; ++j) {
        const int pk = 32 * kt + 8 * q + j;
        const int hr = 32 * (pk >> 5) + 16 * (pk & 1) + ((pk & 31) >> 1);
        fr[j] = (_Float16)Whrz[(size_t)hr * 256 + g];
        fz[j] = (_Float16)Whrz[(size_t)hr * 256 + 128 + g];
        fn[j] = (_Float16)Whn[(size_t)hr * 128 + g];
      }
      Bhr[tu][kt] = __builtin_bit_cast(f32x4, fr);
      Bhz[tu][kt] = __builtin_bit_cast(f32x4, fz);
      Bhn[tu][kt] = __builtin_bit_cast(f32x4, fn);
    }
    #pragma unroll
    for (int kt = 0; kt < 2; ++kt) {
      half8 fr, fz, fn;
      #pragma unroll
      for (int j = 0; j < 8; ++j) {
        const int k = 32 * kt + 8 * q + j;
        fr[j] = (_Float16)Wi[(size_t)k * 384 + g];
        fz[j] = (_Float16)Wi[(size_t)k * 384 + 128 + g];
        fn[j] = (_Float16)Wi[(size_t)k * 384 + 256 + g];
      }
      Bxr[tu][kt] = __builtin_bit_cast(f32x4, fr);
      Bxz[tu][kt] = __builtin_bit_cast(f32x4, fz);
      Bxn[tu][kt] = __builtin_bit_cast(f32x4, fn);
    }
    const float br = bi[g], bz = bi[128 + g];
    const float bx = bi[256 + g], bh = bn[g];
    biasR[tu]  = f32x4{br, br, br, br};
    biasZ[tu]  = f32x4{bz, bz, bz, bz};
    biasHN[tu] = f32x4{bh, bh, bh, bh};
    biasXN[tu] = f32x4{bx, bx, bx, bx};
  }

  // A-frag byte offsets (row = n16, k-chunk = q), swizzled
  int hAoff[4], xAoff[2];
  #pragma unroll
  for (int kt = 0; kt < 4; ++kt)
    hAoff[kt] = (n16 * 256 + kt * 64 + q * 16) ^ ((n16 & 7) << 4);
  #pragma unroll
  for (int kt = 0; kt < 2; ++kt)
    xAoff[kt] = (n16 * 128 + kt * 64 + q * 16) ^ ((n16 & 7) << 4);

  // x staging mapping: thread -> (row, 4-feature group)
  const int srow  = tid >> 4;
  const int sc    = tid & 15;
  const int sbyte = (srow * 128 + sc * 8) ^ ((srow & 7) << 4);

  // ---- init: h slot0 = 0; stage x[0],x[1]; preload x[2],x[3] ----
  *(f32x4*)((char*)h_lds[0] + tid * 16) = f32x4{0.f, 0.f, 0.f, 0.f};
  #pragma unroll
  for (int s = 0; s < 2; ++s) {
    const float4 v =
        *(const float4*)(x + ((size_t)s * BB + brow0 + srow) * FF + sc * 4);
    half4 hf;
    hf[0] = (_Float16)v.x; hf[1] = (_Float16)v.y;
    hf[2] = (_Float16)v.z; hf[3] = (_Float16)v.w;
    *(half4*)((char*)x_lds[s] + sbyte) = hf;
  }
  const float4* xsrc =
      (const float4*)(x + ((size_t)2 * BB + brow0 + srow) * FF + sc * 4);
  float4 xva = xsrc[0];              // x[2]
  float4 xvb = xsrc[(size_t)RS];     // x[3]
  xsrc += 2 * (size_t)RS;            // -> x[4]

  f32x4 hold0 = f32x4{0.f, 0.f, 0.f, 0.f};   // h_old fp32, reg-resident
  f32x4 hold1 = f32x4{0.f, 0.f, 0.f, 0.f};
  float* outp = out + ((size_t)brow0 + q * 4) * HH + 32 * w + n16;
  __syncthreads();

#define STEP(P, XV)                                                         \
  {                                                                         \
    const int t_ = tbase + (P);                                             \
    const char* hb = (const char*)h_lds[(P) & 1];                           \
    const char* xb = (const char*)x_lds[(P) & 3];                           \
    f32x4 Ah0 = *(const f32x4*)(hb + hAoff[0]);                             \
    f32x4 Ah1 = *(const f32x4*)(hb + hAoff[1]);                             \
    f32x4 Ah2 = *(const f32x4*)(hb + hAoff[2]);                             \
    f32x4 Ah3 = *(const f32x4*)(hb + hAoff[3]);                             \
    f32x4 Ax0 = *(const f32x4*)(xb + xAoff[0]);                             \
    f32x4 Ax1 = *(const f32x4*)(xb + xAoff[1]);                             \
    if (t_ + 2 < TT) {                                                      \
      half4 hf;                                                             \
      hf[0] = (_Float16)XV.x; hf[1] = (_Float16)XV.y;                       \
      hf[2] = (_Float16)XV.z; hf[3] = (_Float16)XV.w;                       \
      *(half4*)((char*)x_lds[((P) + 2) & 3] + sbyte) = hf;   /* x[t+2] */   \
    }                                                                       \
    if (t_ + 4 < TT) { XV = *xsrc; xsrc += RS; }             /* x[t+4] */   \
    f32x4 Cr0 = mf(Ah0, Bhr[0][0], biasR[0]);                               \
    Cr0 = mf(Ah1, Bhr[0][1], Cr0); Cr0 = mf(Ah2, Bhr[0][2], Cr0);           \
    Cr0 = mf(Ah3, Bhr[0][3], Cr0); Cr0 = mf(Ax0, Bxr[0][0], Cr0);           \
    Cr0 = mf(Ax1, Bxr[0][1], Cr0);                                          \
    f32x4 Cz0 = mf(Ah0, Bhz[0][0], biasZ[0]);                               \
    Cz0 = mf(Ah1, Bhz[0][1], Cz0); Cz0 = mf(Ah2, Bhz[0][2], Cz0);           \
    Cz0 = mf(Ah3, Bhz[0][3], Cz0); Cz0 = mf(Ax0, Bxz[0][0], Cz0);           \
    Cz0 = mf(Ax1, Bxz[0][1], Cz0);                                          \
    f32x4 Ch0 = mf(Ah0, Bhn[0][0], biasHN[0]);                              \
    Ch0 = mf(Ah1, Bhn[0][1], Ch0); Ch0 = mf(Ah2, Bhn[0][2], Ch0);           \
    Ch0 = mf(Ah3, Bhn[0][3], Ch0);                                          \
    f32x4 Cx0 = mf(Ax0, Bxn[0][0], biasXN[0]);                              \
    Cx0 = mf(Ax1, Bxn[0][1], Cx0);                                          \
    f32x4 Cr1 = mf(Ah0, Bhr[1][0], biasR[1]);                               \
    Cr1 = mf(Ah1, Bhr[1][1], Cr1); Cr1 = mf(Ah2, Bhr[1][2], Cr1);           \
    Cr1 = mf(Ah3, Bhr[1][3], Cr1); Cr1 = mf(Ax0, Bxr[1][0], Cr1);           \
    Cr1 = mf(Ax1, Bxr[1][1], Cr1);                                          \
    f32x4 Cz1 = mf(Ah0, Bhz[1][0], biasZ[1]);                               \
    Cz1 = mf(Ah1, Bhz[1][1], Cz1); Cz1 = mf(Ah2, Bhz[1][2], Cz1);           \
    Cz1 = mf(Ah3, Bhz[1][3], Cz1); Cz1 = mf(Ax0, Bxz[1][0], Cz1);           \
    Cz1 = mf(Ax1, Bxz[1][1], Cz1);                                          \
    f32x4 Ch1 = mf(Ah0, Bhn[1][0], biasHN[1]);                              \
    Ch1 = mf(Ah1, Bhn[1][1], Ch1); Ch1 = mf(Ah2, Bhn[1][2], Ch1);           \
    Ch1 = mf(Ah3, Bhn[1][3], Ch1);                                          \
    f32x4 Cx1 = mf(Ax0, Bxn[1][0], biasXN[1]);                              \
    Cx1 = mf(Ax1, Bxn[1][1], Cx1);                                          \
    float nh0[4], nh1[4];                                                   \
    _Pragma("unroll")                                                       \
    for (int i = 0; i < 4; ++i) {                                           \
      { const float rg = FRCP(1.0f + __expf(-Cr0[i]));                      \
        const float zg = FRCP(1.0f + __expf(-Cz0[i]));                      \
        const float na = Cx0[i] + rg * Ch0[i];                              \
        const float ng = 1.0f - 2.0f * FRCP(__expf(2.0f * na) + 1.0f);      \
        const float hv = zg * (hold0[i] - ng) + ng;                         \
        nh0[i] = hv; hold0[i] = hv; }                                       \
      { const float rg = FRCP(1.0f + __expf(-Cr1[i]));                      \
        const float zg = FRCP(1.0f + __expf(-Cz1[i]));                      \
        const float na = Cx1[i] + rg * Ch1[i];                              \
        const float ng = 1.0f - 2.0f * FRCP(__expf(2.0f * na) + 1.0f);      \
        const float hv = zg * (hold1[i] - ng) + ng;                         \
        nh1[i] = hv; hold1[i] = hv; }                                       \
    }                                                                       \
    _Pragma("unroll")                                                       \
    for (int i = 0; i < 4; ++i) {                                           \
      const int m_ = q * 4 + i;                                             \
      const int wb = (m_ * 256 + 64 * w + 4 * n16) ^ ((m_ & 7) << 4);       \
      *(h2v*)((char*)h_lds[((P) + 1) & 1] + wb) =                           \
          h2v{(_Float16)nh0[i], (_Float16)nh1[i]};                          \
      outp[(size_t)i * HH] = nh0[i];                                        \
      outp[(size_t)i * HH + 16] = nh1[i];                                   \
    }                                                                       \
    outp += (size_t)BB * HH;                                                \
    step_barrier();                                                         \
  }

  for (int tbase = 0; tbase < TT; tbase += 4) {
    PINS();
    STEP(0, xva)
    STEP(1, xvb)
    STEP(2, xva)
    STEP(3, xvb)
  }
#undef STEP
}

extern "C" void kernel_launch(void* const* d_in, const int* in_sizes, int n_in,
                              void* d_out, int out_size, void* d_ws, size_t ws_size,
                              hipStream_t stream) {
  const float* x    = (const float*)d_in[0];
  const float* Wi   = (const float*)d_in[1];
  const float* bi   = (const float*)d_in[2];
  const float* Whrz = (const float*)d_in[3];
  const float* Whn  = (const float*)d_in[4];
  const float* bn   = (const float*)d_in[5];
  float* out = (float*)d_out;

  gru_scan_kernel<<<dim3(NBLK), dim3(NT), 0, stream>>>(
      x, Wi, bi, Whrz, Whn, bn, out);
}

// Round 15
// 1406.279 us; speedup vs baseline: 1.1186x; 1.1186x over previous
//
#include <hip/hip_runtime.h>

#define TT 2048
#define BB 256
#define FF 64
#define HH 128
#define NT 512            // 8 waves; wave w owns units [16w, 16w+16)
#define MROWS 16          // batch rows per block = MFMA M
#define NBLK (BB / MROWS) // 16 blocks
#define RS (BB * FF / 4)  // x row stride in float4

typedef _Float16 half8 __attribute__((ext_vector_type(8)));
typedef _Float16 half4 __attribute__((ext_vector_type(4)));
typedef float    f32x4 __attribute__((ext_vector_type(4)));

#if __has_builtin(__builtin_amdgcn_rcpf)
#define FRCP(v) __builtin_amdgcn_rcpf(v)
#else
#define FRCP(v) (1.0f / (v))
#endif

// D = A(16x32 f16) * B(32x16 f16) + C(f32). Conventions identical to the
// round-14 kernel which passed correctness (absmax 0.0039).
__device__ __forceinline__ f32x4 mf(f32x4 a, f32x4 b, f32x4 c) {
  return __builtin_amdgcn_mfma_f32_16x16x32_f16(
      __builtin_bit_cast(half8, a), __builtin_bit_cast(half8, b), c, 0, 0, 0);
}

// Hot-loop barrier without the vmcnt(0) drain (r9: proven equivalent).
__device__ __forceinline__ void step_barrier() {
  asm volatile("s_waitcnt lgkmcnt(0)" ::: "memory");
  __builtin_amdgcn_s_barrier();
  __builtin_amdgcn_sched_barrier(0);
}

// In-loop pins (r7-proven): B-fragments stay loop-carried in VGPRs.
#define PINS()                                                              \
  do {                                                                      \
    _Pragma("unroll") for (int _k = 0; _k < 4; ++_k) {                      \
      asm volatile("" : "+v"(Bhr[_k]), "+v"(Bhz[_k]), "+v"(Bhn2[_k]));      \
    }                                                                       \
    _Pragma("unroll") for (int _k = 0; _k < 2; ++_k) {                      \
      asm volatile("" : "+v"(Bxr[_k]), "+v"(Bxz[_k]), "+v"(Bxn2[_k]));      \
    }                                                                       \
  } while (0)

__global__ void __launch_bounds__(NT)
__attribute__((amdgpu_waves_per_eu(2, 2)))
gru_scan_kernel(const float* __restrict__ x,     // [T,B,F]
                const float* __restrict__ Wi,    // [F,3H] r|z|n
                const float* __restrict__ bi,    // [3H]
                const float* __restrict__ Whrz,  // [H,2H] r|z
                const float* __restrict__ Whn,   // [H,H]
                const float* __restrict__ bn,    // [H]
                float* __restrict__ out)         // [T,B,H]
{
  const int tid   = threadIdx.x;
  const int w     = tid >> 6;     // wave 0..7
  const int l     = tid & 63;
  const int n16   = l & 15;       // C col within tile / A row
  const int q     = l >> 4;       // k-chunk group / C row group
  const int u     = 16 * w + n16; // hidden unit 0..127 (this thread's column)
  const int brow0 = blockIdx.x * MROWS;

  // A-operand staging (f16), XOR-swizzled rows: byte ^= ((row&7)<<4).
  __shared__ __align__(16) _Float16 h_lds[2][MROWS * HH];  // 8 KB
  __shared__ __align__(16) _Float16 x_lds[4][MROWS * FF];  // 8 KB

  // ---- B-fragments: wave w covers units [16w,16w+16) for r, z, hn, xn.
  // Natural k order; lane (n16,q) holds k = 32kt + 8q + j, col = u. ----
  f32x4 Bhr[4], Bhz[4], Bhn2[4];
  f32x4 Bxr[2], Bxz[2], Bxn2[2];
  #pragma unroll
  for (int kt = 0; kt < 4; ++kt) {
    half8 fr, fz, fn;
    #pragma unroll
    for (int j = 0; j < 8; ++j) {
      const int k = 32 * kt + 8 * q + j;       // 0..127 (h k-space)
      fr[j] = (_Float16)Whrz[(size_t)k * 256 + u];
      fz[j] = (_Float16)Whrz[(size_t)k * 256 + 128 + u];
      fn[j] = (_Float16)Whn[(size_t)k * 128 + u];
    }
    Bhr[kt]  = __builtin_bit_cast(f32x4, fr);
    Bhz[kt]  = __builtin_bit_cast(f32x4, fz);
    Bhn2[kt] = __builtin_bit_cast(f32x4, fn);
  }
  #pragma unroll
  for (int kt = 0; kt < 2; ++kt) {
    half8 fr, fz, fn;
    #pragma unroll
    for (int j = 0; j < 8; ++j) {
      const int k = 32 * kt + 8 * q + j;       // 0..63 (x k-space)
      fr[j] = (_Float16)Wi[(size_t)k * 384 + u];
      fz[j] = (_Float16)Wi[(size_t)k * 384 + 128 + u];
      fn[j] = (_Float16)Wi[(size_t)k * 384 + 256 + u];
    }
    Bxr[kt]  = __builtin_bit_cast(f32x4, fr);
    Bxz[kt]  = __builtin_bit_cast(f32x4, fz);
    Bxn2[kt] = __builtin_bit_cast(f32x4, fn);
  }
  const float bR = bi[u], bZ = bi[128 + u], bX = bi[256 + u], bH = bn[u];
  const f32x4 biasR  = f32x4{bR, bR, bR, bR};
  const f32x4 biasZ  = f32x4{bZ, bZ, bZ, bZ};
  const f32x4 biasX  = f32x4{bX, bX, bX, bX};
  const f32x4 biasH  = f32x4{bH, bH, bH, bH};

  // A-fragment byte offsets (row = n16), swizzled
  int hAoff[4], xAoff[2];
  #pragma unroll
  for (int kt = 0; kt < 4; ++kt)
    hAoff[kt] = (n16 * 256 + kt * 64 + q * 16) ^ ((n16 & 7) << 4);
  #pragma unroll
  for (int kt = 0; kt < 2; ++kt)
    xAoff[kt] = (n16 * 128 + kt * 64 + q * 16) ^ ((n16 & 7) << 4);

  // h'-write byte offsets (4 rows, this thread's unit), same swizzle fn
  int hWoff[4];
  #pragma unroll
  for (int i = 0; i < 4; ++i) {
    const int row = q * 4 + i;
    hWoff[i] = (row * 256 + 2 * u) ^ ((row & 7) << 4);
  }

  // x staging: threads 0..255, thread -> (row, 4-feature group)
  const int srow  = (tid & 255) >> 4;
  const int sc    = tid & 15;
  const int sbyte = (srow * 128 + sc * 8) ^ ((srow & 7) << 4);
  const bool loader = (tid < 256);

  // ---- init: h slot0 = 0; stage x[0],x[1]; preload x[2],x[3] ----
  if (tid < 256) {
    *(f32x4*)((char*)h_lds[0] + tid * 16) = f32x4{0.f, 0.f, 0.f, 0.f};
  }
  if (loader) {
    #pragma unroll
    for (int s = 0; s < 2; ++s) {
      const float4 v =
          *(const float4*)(x + ((size_t)s * BB + brow0 + srow) * FF + sc * 4);
      half4 hf;
      hf[0] = (_Float16)v.x; hf[1] = (_Float16)v.y;
      hf[2] = (_Float16)v.z; hf[3] = (_Float16)v.w;
      *(half4*)((char*)x_lds[s] + sbyte) = hf;
    }
  }
  const float4* xsrc =
      (const float4*)(x + ((size_t)2 * BB + brow0 + srow) * FF + sc * 4);
  float4 xva, xvb;
  if (loader) {
    xva = xsrc[0];              // x[2]
    xvb = xsrc[(size_t)RS];     // x[3]
    xsrc += 2 * (size_t)RS;     // -> x[4]
  }

  f32x4 hold = f32x4{0.f, 0.f, 0.f, 0.f};   // h_old fp32, register-resident
  float* outp = out + ((size_t)brow0 + q * 4) * HH + u;
  __syncthreads();

#define STEP(P, XV)                                                         \
  {                                                                         \
    const int t_ = tbase + (P);                                             \
    const char* hb = (const char*)h_lds[(P) & 1];                           \
    const char* xb = (const char*)x_lds[(P) & 3];                           \
    f32x4 Ah0 = *(const f32x4*)(hb + hAoff[0]);                             \
    f32x4 Ah1 = *(const f32x4*)(hb + hAoff[1]);                             \
    f32x4 Ah2 = *(const f32x4*)(hb + hAoff[2]);                             \
    f32x4 Ah3 = *(const f32x4*)(hb + hAoff[3]);                             \
    f32x4 Ax0 = *(const f32x4*)(xb + xAoff[0]);                             \
    f32x4 Ax1 = *(const f32x4*)(xb + xAoff[1]);                             \
    if (loader) {                                                           \
      if (t_ + 2 < TT) {                                                    \
        half4 hf;                                                           \
        hf[0] = (_Float16)XV.x; hf[1] = (_Float16)XV.y;                     \
        hf[2] = (_Float16)XV.z; hf[3] = (_Float16)XV.w;                     \
        *(half4*)((char*)x_lds[((P) + 2) & 3] + sbyte) = hf; /* x[t+2] */   \
      }                                                                     \
      if (t_ + 4 < TT) { XV = *xsrc; xsrc += RS; }           /* x[t+4] */   \
    }                                                                       \
    f32x4 Cr = mf(Ah0, Bhr[0], biasR);                                      \
    Cr = mf(Ah1, Bhr[1], Cr); Cr = mf(Ah2, Bhr[2], Cr);                     \
    Cr = mf(Ah3, Bhr[3], Cr);                                               \
    Cr = mf(Ax0, Bxr[0], Cr); Cr = mf(Ax1, Bxr[1], Cr);                     \
    f32x4 Cz = mf(Ah0, Bhz[0], biasZ);                                      \
    Cz = mf(Ah1, Bhz[1], Cz); Cz = mf(Ah2, Bhz[2], Cz);                     \
    Cz = mf(Ah3, Bhz[3], Cz);                                               \
    Cz = mf(Ax0, Bxz[0], Cz); Cz = mf(Ax1, Bxz[1], Cz);                     \
    f32x4 Chn = mf(Ah0, Bhn2[0], biasH);                                    \
    Chn = mf(Ah1, Bhn2[1], Chn); Chn = mf(Ah2, Bhn2[2], Chn);               \
    Chn = mf(Ah3, Bhn2[3], Chn);                                            \
    f32x4 Cxn = mf(Ax0, Bxn2[0], biasX);                                    \
    Cxn = mf(Ax1, Bxn2[1], Cxn);                                            \
    /* gates on in-register fragments: 5 trans per element */               \
    _Pragma("unroll")                                                       \
    for (int i = 0; i < 4; ++i) {                                           \
      const float A_ = __expf(-Cr[i]);            /* e^-pr */               \
      const float rg = FRCP(1.0f + A_);                                     \
      const float B_ = __expf(-Cz[i]);            /* e^-pz */               \
      const float na = Cxn[i] + rg * Chn[i];                                \
      const float E_ = __expf(2.0f * na);         /* e^2na */               \
      /* h' = [h(E+1) + B(E-1)] / [(E+1)(1+B)]  (== z*h + (1-z)*tanh(na)) */\
      const float Ep1 = E_ + 1.0f;                                          \
      const float num = hold[i] * Ep1 + B_ * (E_ - 1.0f);                   \
      const float hv  = num * FRCP(Ep1 * (1.0f + B_));                      \
      hold[i] = hv;                                                         \
      *(_Float16*)((char*)h_lds[((P) + 1) & 1] + hWoff[i]) = (_Float16)hv;  \
      outp[(size_t)i * HH] = hv;                                            \
    }                                                                       \
    outp += (size_t)BB * HH;                                                \
    step_barrier();                                                         \
  }

  for (int tbase = 0; tbase < TT; tbase += 4) {
    PINS();
    STEP(0, xva)
    STEP(1, xvb)
    STEP(2, xva)
    STEP(3, xvb)
  }
#undef STEP
}

extern "C" void kernel_launch(void* const* d_in, const int* in_sizes, int n_in,
                              void* d_out, int out_size, void* d_ws, size_t ws_size,
                              hipStream_t stream) {
  const float* x    = (const float*)d_in[0];
  const float* Wi   = (const float*)d_in[1];
  const float* bi   = (const float*)d_in[2];
  const float* Whrz = (const float*)d_in[3];
  const float* Whn  = (const float*)d_in[4];
  const float* bn   = (const float*)d_in[5];
  float* out = (float*)d_out;

  gru_scan_kernel<<<dim3(NBLK), dim3(NT), 0, stream>>>(
      x, Wi, bi, Whrz, Whn, bn, out);
}

// Round 16
// 892.912 us; speedup vs baseline: 1.7617x; 1.5749x over previous
//
#include <hip/hip_runtime.h>

#define TT 2048
#define BB 256
#define FF 64
#define HH 128
#define NT 512            // 8 waves; wave w owns units [16w, 16w+16)
#define MR 4              // valid batch rows per block
#define NBLK (BB / MR)    // 64 blocks
#define RS (BB * FF / 4)  // x row stride in float4
#define HSTR 320          // LDS row stride (bytes): rows r, r+2 share banks (2-way, free)

typedef _Float16 half8 __attribute__((ext_vector_type(8)));
typedef _Float16 half4 __attribute__((ext_vector_type(4)));
typedef float    f32x4 __attribute__((ext_vector_type(4)));

#if __has_builtin(__builtin_amdgcn_rcpf)
#define FRCP(v) __builtin_amdgcn_rcpf(v)
#else
#define FRCP(v) (1.0f / (v))
#endif

// D = A(16x32 f16) * B(32x16 f16) + C(f32). Same operand conventions as the
// round-14/15 kernels (both passed, absmax 0.0039).
__device__ __forceinline__ f32x4 mf(f32x4 a, f32x4 b, f32x4 c) {
  return __builtin_amdgcn_mfma_f32_16x16x32_f16(
      __builtin_bit_cast(half8, a), __builtin_bit_cast(half8, b), c, 0, 0, 0);
}

// Hot-loop barrier without the vmcnt(0) drain (r9: proven equivalent).
__device__ __forceinline__ void step_barrier() {
  asm volatile("s_waitcnt lgkmcnt(0)" ::: "memory");
  __builtin_amdgcn_s_barrier();
  __builtin_amdgcn_sched_barrier(0);
}

__global__ void __launch_bounds__(NT)
__attribute__((amdgpu_waves_per_eu(2, 2)))
gru_scan_kernel(const float* __restrict__ x,     // [T,B,F]
                const float* __restrict__ Wi,    // [F,3H] r|z|n
                const float* __restrict__ bi,    // [3H]
                const float* __restrict__ Whrz,  // [H,2H] r|z
                const float* __restrict__ Whn,   // [H,H]
                const float* __restrict__ bn,    // [H]
                float* __restrict__ out)         // [T,B,H]
{
  const int tid   = threadIdx.x;
  const int w     = tid >> 6;     // wave 0..7
  const int l     = tid & 63;
  const int n16   = l & 15;       // C col within tile / A row m
  const int q     = l >> 4;       // k-chunk group; also this lane's batch row
  const int u     = 16 * w + n16; // hidden unit (this thread's column)
  const int rr    = n16 & 3;      // replicated A row -> batch row for A reads
  const int brow0 = blockIdx.x * MR;

  // Compact 4-row staging, f16, row stride 320B (16B-aligned; rows r and r+2
  // bank-alias 2-way which is free). Data bytes [0,256) of each row.
  __shared__ __align__(16) char h_lds[2][MR * HSTR];   // 2 x 1280 B
  __shared__ __align__(16) char x_lds[4][MR * HSTR];   // 4 x 1280 B

  // ---- B-fragments (natural k order, col u). NO pins: MFMA reads AGPRs
  // natively; r15's "+v" pins forced AGPR<->VGPR churn. ----
  f32x4 Bhr[4], Bhz[4], Bhn2[4];
  f32x4 Bxr[2], Bxz[2], Bxn2[2];
  #pragma unroll
  for (int kt = 0; kt < 4; ++kt) {
    half8 fr, fz, fn;
    #pragma unroll
    for (int j = 0; j < 8; ++j) {
      const int k = 32 * kt + 8 * q + j;       // 0..127
      fr[j] = (_Float16)Whrz[(size_t)k * 256 + u];
      fz[j] = (_Float16)Whrz[(size_t)k * 256 + 128 + u];
      fn[j] = (_Float16)Whn[(size_t)k * 128 + u];
    }
    Bhr[kt]  = __builtin_bit_cast(f32x4, fr);
    Bhz[kt]  = __builtin_bit_cast(f32x4, fz);
    Bhn2[kt] = __builtin_bit_cast(f32x4, fn);
  }
  #pragma unroll
  for (int kt = 0; kt < 2; ++kt) {
    half8 fr, fz, fn;
    #pragma unroll
    for (int j = 0; j < 8; ++j) {
      const int k = 32 * kt + 8 * q + j;       // 0..63
      fr[j] = (_Float16)Wi[(size_t)k * 384 + u];
      fz[j] = (_Float16)Wi[(size_t)k * 384 + 128 + u];
      fn[j] = (_Float16)Wi[(size_t)k * 384 + 256 + u];
    }
    Bxr[kt]  = __builtin_bit_cast(f32x4, fr);
    Bxz[kt]  = __builtin_bit_cast(f32x4, fz);
    Bxn2[kt] = __builtin_bit_cast(f32x4, fn);
  }
  const float bR = bi[u], bZ = bi[128 + u], bX = bi[256 + u], bH = bn[u];
  const f32x4 biasR = f32x4{bR, bR, bR, bR};
  const f32x4 biasZ = f32x4{bZ, bZ, bZ, bZ};
  const f32x4 biasX = f32x4{bX, bX, bX, bX};
  const f32x4 biasH = f32x4{bH, bH, bH, bH};

  // A-fragment byte offsets: row rr, k-chunk (kt, q); byte = rr*HSTR + 2*k.
  int hA[4], xA[2];
  #pragma unroll
  for (int kt = 0; kt < 4; ++kt) hA[kt] = rr * HSTR + kt * 64 + q * 16;
  #pragma unroll
  for (int kt = 0; kt < 2; ++kt) xA[kt] = rr * HSTR + kt * 64 + q * 16;

  // h'-write: this lane's (batch row q, unit u)
  const int hW = q * HSTR + 2 * u;

  // x staging: 64 loader threads -> (row, 4-feature group)
  const bool loader = (tid < 64);
  const int  srow   = tid >> 4;   // 0..3 (loader only)
  const int  sc     = tid & 15;
  const int  sbyte  = srow * HSTR + sc * 8;

  // ---- init: h[0] buffer = 0; stage x[0],x[1]; prefetch x[2],x[3] ----
  if (loader) {
    *(f32x4*)(h_lds[0] + srow * HSTR + sc * 16) = f32x4{0.f, 0.f, 0.f, 0.f};
    #pragma unroll
    for (int s = 0; s < 2; ++s) {
      const float4 v =
          *(const float4*)(x + ((size_t)s * BB + brow0 + srow) * FF + sc * 4);
      half4 hf;
      hf[0] = (_Float16)v.x; hf[1] = (_Float16)v.y;
      hf[2] = (_Float16)v.z; hf[3] = (_Float16)v.w;
      *(half4*)(x_lds[s] + sbyte) = hf;
    }
  }
  const float4* xsrc =
      (const float4*)(x + ((size_t)2 * BB + brow0 + srow) * FF + sc * 4);
  float4 xva, xvb;
  if (loader) {
    xva = xsrc[0];              // x[2]
    xvb = xsrc[(size_t)RS];     // x[3]
    xsrc += 2 * (size_t)RS;     // -> x[4]
  }

  float h_old = 0.0f;           // this lane's (row q, unit u), fp32
  float* outp = out + ((size_t)brow0 + q) * HH + u;
  __syncthreads();

#define STEP(P, XV)                                                         \
  {                                                                         \
    const int t_ = tbase + (P);                                             \
    const char* hb = h_lds[(P) & 1];                                        \
    const char* xb = x_lds[(P) & 3];                                        \
    f32x4 Ah0 = *(const f32x4*)(hb + hA[0]);                                \
    f32x4 Ah1 = *(const f32x4*)(hb + hA[1]);                                \
    f32x4 Ah2 = *(const f32x4*)(hb + hA[2]);                                \
    f32x4 Ah3 = *(const f32x4*)(hb + hA[3]);                                \
    f32x4 Ax0 = *(const f32x4*)(xb + xA[0]);                                \
    f32x4 Ax1 = *(const f32x4*)(xb + xA[1]);                                \
    if (loader) {                                                           \
      if (t_ + 2 < TT) {                                                    \
        half4 hf;                                                           \
        hf[0] = (_Float16)XV.x; hf[1] = (_Float16)XV.y;                     \
        hf[2] = (_Float16)XV.z; hf[3] = (_Float16)XV.w;                     \
        *(half4*)(x_lds[((P) + 2) & 3] + sbyte) = hf;        /* x[t+2] */   \
      }                                                                     \
      if (t_ + 4 < TT) { XV = *xsrc; xsrc += RS; }           /* x[t+4] */   \
    }                                                                       \
    f32x4 Cr = mf(Ah0, Bhr[0], biasR);                                      \
    Cr = mf(Ah1, Bhr[1], Cr); Cr = mf(Ah2, Bhr[2], Cr);                     \
    Cr = mf(Ah3, Bhr[3], Cr);                                               \
    Cr = mf(Ax0, Bxr[0], Cr); Cr = mf(Ax1, Bxr[1], Cr);                     \
    f32x4 Cz = mf(Ah0, Bhz[0], biasZ);                                      \
    Cz = mf(Ah1, Bhz[1], Cz); Cz = mf(Ah2, Bhz[2], Cz);                     \
    Cz = mf(Ah3, Bhz[3], Cz);                                               \
    Cz = mf(Ax0, Bxz[0], Cz); Cz = mf(Ax1, Bxz[1], Cz);                     \
    f32x4 Chn = mf(Ah0, Bhn2[0], biasH);                                    \
    Chn = mf(Ah1, Bhn2[1], Chn); Chn = mf(Ah2, Bhn2[2], Chn);               \
    Chn = mf(Ah3, Bhn2[3], Chn);                                            \
    f32x4 Cxn = mf(Ax0, Bxn2[0], biasX);                                    \
    Cxn = mf(Ax1, Bxn2[1], Cxn);                                            \
    /* replicated rows: C reg i == batch row i in EVERY lane; this lane    */\
    /* gates (row q, col n16) via constant-index selects (no shuffles).    */\
    const float cr  = (q < 2) ? ((q == 0) ? Cr[0]  : Cr[1])                 \
                              : ((q == 2) ? Cr[2]  : Cr[3]);                \
    const float cz  = (q < 2) ? ((q == 0) ? Cz[0]  : Cz[1])                 \
                              : ((q == 2) ? Cz[2]  : Cz[3]);                \
    const float chn = (q < 2) ? ((q == 0) ? Chn[0] : Chn[1])                \
                              : ((q == 2) ? Chn[2] : Chn[3]);               \
    const float cxn = (q < 2) ? ((q == 0) ? Cxn[0] : Cxn[1])                \
                              : ((q == 2) ? Cxn[2] : Cxn[3]);               \
    const float A_ = __expf(-cr);                                           \
    const float rg = FRCP(1.0f + A_);                                       \
    const float B_ = __expf(-cz);                                           \
    const float na = cxn + rg * chn;                                        \
    const float E_ = __expf(2.0f * na);                                     \
    const float Ep1 = E_ + 1.0f;                                            \
    const float num = h_old * Ep1 + B_ * (E_ - 1.0f);                       \
    const float hv  = num * FRCP(Ep1 * (1.0f + B_));                        \
    h_old = hv;                                                             \
    *(_Float16*)(h_lds[((P) + 1) & 1] + hW) = (_Float16)hv;                 \
    *outp = hv;                                                             \
    outp += (size_t)BB * HH;                                                \
    step_barrier();                                                         \
  }

  for (int tbase = 0; tbase < TT; tbase += 4) {
    STEP(0, xva)
    STEP(1, xvb)
    STEP(2, xva)
    STEP(3, xvb)
  }
#undef STEP
}

extern "C" void kernel_launch(void* const* d_in, const int* in_sizes, int n_in,
                              void* d_out, int out_size, void* d_ws, size_t ws_size,
                              hipStream_t stream) {
  const float* x    = (const float*)d_in[0];
  const float* Wi   = (const float*)d_in[1];
  const float* bi   = (const float*)d_in[2];
  const float* Whrz = (const float*)d_in[3];
  const float* Whn  = (const float*)d_in[4];
  const float* bn   = (const float*)d_in[5];
  float* out = (float*)d_out;

  gru_scan_kernel<<<dim3(NBLK), dim3(NT), 0, stream>>>(
      x, Wi, bi, Whrz, Whn, bn, out);
}